// Round 24
// baseline (82.350 us; speedup 1.0000x reference)
//
#include <hip/hip_runtime.h>
#include <hip/hip_bf16.h>
#include <math.h>

// B=4, NB=2048 -> 8192 leaf blocks of L=16 tokens x C=128; H=8 heads x D=16.
// SINGLE KERNEL (prep folded away — each WG converts its own weight tiles
// f32->bf16 in the prologue; no d_ws, no serial pre-dispatch).
// 512 threads (8 waves), NITER=16 blocks/WG (grid 512 = 2 WGs/CU), 2 barriers/iter.
// q/k via SWAPPED-operand MFMA (q/k/v/P in registers); Bq/Bk/Bv/Bg/Wt ALL
// register-resident; edge-gate MLP on matrix cores; ballot row-sum; max-free
// softmax; native packed f32->bf16 conversions; swapped proj -> f32x4 store.
typedef __attribute__((ext_vector_type(8))) short bf16x8;
typedef __attribute__((ext_vector_type(4))) short bf16x4;
typedef __attribute__((ext_vector_type(4))) float f32x4;
typedef __attribute__((ext_vector_type(8))) float f32x8;
typedef __attribute__((ext_vector_type(4))) unsigned short us4;
typedef __attribute__((ext_vector_type(4))) __bf16 bfv4;
typedef __attribute__((ext_vector_type(8))) __bf16 bfv8;

#define NITER 16

static __device__ __forceinline__ bf16x4 cvt4(f32x4 v) {
    union { bfv4 b; bf16x4 s; } u;
    u.b = __builtin_convertvector(v, bfv4);
    return u.s;
}
static __device__ __forceinline__ us4 cvt4u(f32x4 v) {
    union { bfv4 b; us4 s; } u;
    u.b = __builtin_convertvector(v, bfv4);
    return u.s;
}
static __device__ __forceinline__ bf16x8 cvt8(f32x8 v) {
    union { bfv8 b; bf16x8 s; } u;
    u.b = __builtin_convertvector(v, bfv8);
    return u.s;
}
static __device__ __forceinline__ float bf2f(unsigned short u) {
    union { unsigned int i; float f; } cv;
    cv.i = ((unsigned int)u) << 16;
    return cv.f;
}
static __device__ __forceinline__ f32x4 MFMA(bf16x8 a, bf16x8 b, f32x4 c) {
    return __builtin_amdgcn_mfma_f32_16x16x32_bf16(a, b, c, 0, 0, 0);
}
static __device__ __forceinline__ f32x4 MFMA16(bf16x4 a, bf16x4 b, f32x4 c) {
#if __has_builtin(__builtin_amdgcn_mfma_f32_16x16x16bf16_1k)
    return __builtin_amdgcn_mfma_f32_16x16x16bf16_1k(a, b, c, 0, 0, 0);
#elif __has_builtin(__builtin_amdgcn_mfma_f32_16x16x16_bf16)
    return __builtin_amdgcn_mfma_f32_16x16x16_bf16(a, b, c, 0, 0, 0);
#else
    f32x4 d;
    asm("v_mfma_f32_16x16x16_bf16 %0, %1, %2, %3"
        : "=v"(d) : "v"(a), "v"(b), "v"(c));
    return d;
#endif
}
static __device__ __forceinline__ float sigmoid_fast(float t) {
    return __builtin_amdgcn_rcpf(1.f + __expf(-t));
}
static __device__ __forceinline__ bf16x8 load_cvt8(const float* p) {
    const f32x4 a = *(const f32x4*)p;
    const f32x4 b = *(const f32x4*)(p + 4);
    f32x8 v;
    v[0] = a[0]; v[1] = a[1]; v[2] = a[2]; v[3] = a[3];
    v[4] = b[0]; v[5] = b[1]; v[6] = b[2]; v[7] = b[3];
    return cvt8(v);
}

__global__ __launch_bounds__(512) void leaf_main(
    const float* __restrict__ x, const int* __restrict__ mask,
    const float* __restrict__ edge,
    const float* __restrict__ Wqkv, const float* __restrict__ bqkv,
    const float* __restrict__ Wproj, const float* __restrict__ bproj,
    const float* __restrict__ eg_w1, const float* __restrict__ eg_b1,
    const float* __restrict__ eg_w2, const float* __restrict__ eg_b2,
    const float* __restrict__ Wbr, const float* __restrict__ bbr,
    float* __restrict__ out)
{
    __shared__ unsigned short xS[16 * 128];      // x stage (bf16, swizzled)
    __shared__ unsigned short mhiS[16 * 136];    // x_mid rounded bf16
    __shared__ unsigned short ewS[8 * 256];      // [h][q*16+k]
    __shared__ float logitS[256];                // [q*16+k]
    // total ~14.3 KB

    const int tid  = threadIdx.x;
    const int lane = tid & 63;
    const int wave = tid >> 6;
    const int c15  = lane & 15;
    const int quad = lane >> 4;
    const int bid0 = blockIdx.x * NITER;
    const int t0 = wave * 2, t1 = wave * 2 + 1;   // this wave's q-row tiles

    // iteration-invariant scalars (q/k biases are per-d = quad*4+r based)
    const f32x4 bqv = *(const f32x4*)&bqkv[wave * 16 + quad * 4];
    const f32x4 bkv = *(const f32x4*)&bqkv[128 + wave * 16 + quad * 4];
    const float bq2 = bqkv[256 + wave * 16 + c15];
    const float bgate = bbr[c15 & 7];
    const f32x4 bpv4 = *(const f32x4*)&bproj[wave * 16 + quad * 4];

    // ---- resident MLP fragments (converted in-kernel) ----
    bf16x4 W1a = {0, 0, 0, 0};    // A[row=j=c15][k=quad*4+r] (k<4 valid)
    if (quad == 0) {
        const f32x4 w1 = *(const f32x4*)&eg_w1[c15 * 4];
        W1a = cvt4(w1);
    }
    bf16x4 W2a = {0, 0, 0, 0};    // A[row=h=c15][k=j=quad*4+r] (h<8 valid)
    if (c15 < 8) {
        const f32x4 w2 = *(const f32x4*)&eg_w2[c15 * 16 + quad * 4];
        W2a = cvt4(w2);
    }
    const f32x4 b1v = *(const f32x4*)&eg_b1[quad * 4];
    f32x4 b2v = {0.f, 0.f, 0.f, 0.f};
    if (quad < 2) b2v = *(const f32x4*)&eg_b2[quad * 4];

    // ---- REGISTER-RESIDENT weight tiles, converted f32->bf16 in prologue ----
    bf16x8 Bq[4], Bk[4], Bv[4], Bg[4], Wt[4];
    {
        const int ko = quad * 8;   // element offset within the 128-wide row
        const float* wq = Wqkv + (wave * 16 + c15) * 128 + ko;           // q rows
        const float* wk = Wqkv + (128 + wave * 16 + c15) * 128 + ko;     // k rows
        const float* wv = Wqkv + (256 + wave * 16 + c15) * 128 + ko;     // v rows
        const float* wp = Wproj + (wave * 16 + c15) * 128 + ko;
        #pragma unroll
        for (int kk = 0; kk < 4; ++kk) {
            Bq[kk] = load_cvt8(wq + kk * 32);
            Bk[kk] = load_cvt8(wk + kk * 32);
            Bv[kk] = load_cvt8(wv + kk * 32);
            Wt[kk] = load_cvt8(wp + kk * 32);
        }
        if (c15 < 8) {     // gate tile rows: Wbr (8 rows), rows 8..15 are zero
            const float* wg = Wbr + c15 * 128 + ko;
            #pragma unroll
            for (int kk = 0; kk < 4; ++kk) Bg[kk] = load_cvt8(wg + kk * 32);
        } else {
            const bf16x8 zf8 = {0, 0, 0, 0, 0, 0, 0, 0};
            #pragma unroll
            for (int kk = 0; kk < 4; ++kk) Bg[kk] = zf8;
        }
    }

    // prologue: block 0 inputs (mask/edge on quad-0 lanes only)
    int mvA = 0, mvB = 0;
    float4 evA = make_float4(0.f, 0.f, 0.f, 0.f);
    float4 evB = make_float4(0.f, 0.f, 0.f, 0.f);
    if (quad == 0) {
        const size_t base = (size_t)bid0 * 256;
        mvA = mask[base + t0 * 16 + c15];
        mvB = mask[base + t1 * 16 + c15];
        evA = *(const float4*)&edge[(base + t0 * 16 + c15) * 4];
        evB = *(const float4*)&edge[(base + t1 * 16 + c15) * 4];
    }
    float4 xv = ((const float4*)(x + (size_t)bid0 * 2048))[tid];
    {
        int row = tid >> 5, c4 = tid & 31;
        int off = row * 128 + (((c4 >> 1) ^ (row & 7)) << 3) + ((c4 & 1) << 2);
        f32x4 vv = {xv.x, xv.y, xv.z, xv.w};
        *(us4*)&xS[off] = cvt4u(vv);
    }
    __syncthreads();   // prologue barrier: x0 staged

    #pragma unroll 1
    for (int it = 0; it < NITER; ++it) {
        const int bid = bid0 + it;
        const bool more = (it + 1 < NITER);

        // next-block loads (retire under this iteration's compute)
        float4 xv_n = make_float4(0.f, 0.f, 0.f, 0.f);
        int mvA_n = 0, mvB_n = 0;
        float4 evA_n = make_float4(0.f, 0.f, 0.f, 0.f);
        float4 evB_n = make_float4(0.f, 0.f, 0.f, 0.f);
        if (more) {
            xv_n = ((const float4*)(x + (size_t)(bid + 1) * 2048))[tid];
            if (quad == 0) {
                const size_t base = (size_t)(bid + 1) * 256;
                mvA_n = mask[base + t0 * 16 + c15];
                mvB_n = mask[base + t1 * 16 + c15];
                evA_n = *(const float4*)&edge[(base + t0 * 16 + c15) * 4];
                evB_n = *(const float4*)&edge[(base + t1 * 16 + c15) * 4];
            }
        }

        // ---- edge-gate MLP on matrix cores: two q-row tiles per wave ----
        #pragma unroll
        for (int tt = 0; tt < 2; ++tt) {
            const int t = tt ? t1 : t0;
            const int mvt = tt ? mvB : mvA;
            const float4 evt = tt ? evB : evA;
            // layer-1 B fragment: B[k=quad*4+r][col=pair_in_row=c15]
            bf16x4 bpB = {0, 0, 0, 0};
            float bp3 = 0.f;
            if (quad == 0) {
                const bool diag = (c15 == t);
                bp3 = diag ? 1.f : evt.w;
                f32x4 bpf = {diag ? 0.f : evt.x, diag ? 0.f : evt.y,
                             diag ? 0.f : evt.z, bp3};
                bpB = cvt4(bpf);
            }
            // mask row (tile == q-row): one ballot, uniform result
            const unsigned long long bl = __ballot(quad == 0 && mvt != 0);
            const unsigned m16 = (unsigned)(bl & 0xFFFFull);
            const bool meff = ((m16 >> c15) & 1u) || (m16 == 0u && c15 == t);
            if (quad == 0)
                logitS[t * 16 + c15] = meff ? bp3 : -INFINITY;
            // hT[j=quad*4+r][pair=c15] = W1 @ bpT  (+b1, gelu)
            f32x4 h1 = {0.f, 0.f, 0.f, 0.f};
            h1 = MFMA16(W1a, bpB, h1);
            f32x4 gv;
            #pragma unroll
            for (int r = 0; r < 4; ++r) {
                float z = h1[r] + b1v[r];
                float u = z * z;
                float w = __builtin_fmaf(-0.0664904f, u, 0.3989423f);
                gv[r] = z * __builtin_fmaf(z, w, 0.5f);
            }
            bf16x4 hB = cvt4(gv);
            // ewT[h=quad*4+r][pair=c15] = W2 @ hT (+b2)
            f32x4 e2 = {0.f, 0.f, 0.f, 0.f};
            e2 = MFMA16(W2a, hB, e2);
            if (quad < 2) {
                #pragma unroll
                for (int r = 0; r < 4; ++r) {
                    float ewv = e2[r] + b2v[r];
                    ewS[(quad * 4 + r) * 256 + t * 16 + c15] =
                        meff ? (unsigned short)(__float_as_uint(ewv) >> 16)
                             : (unsigned short)0;
                }
            }
        }

        // ---- x fragments from xS (serve as A or B operand) ----
        bf16x8 ah[4];
        #pragma unroll
        for (int kk = 0; kk < 4; ++kk) {
            int off = c15 * 128 + (((kk * 4 + quad) ^ (c15 & 7)) << 3);
            ah[kk] = *(const bf16x8*)&xS[off];
        }

        bf16x4 qa, ka, va;
        float vblk;
        float greg[4];

        // ---- tile q: SWAPPED (W as A, x as B) -> Q[tok=c15][d=quad*4+r] ----
        {
            f32x4 acc = {0.f, 0.f, 0.f, 0.f};
            #pragma unroll
            for (int kk = 0; kk < 4; ++kk) acc = MFMA(Bq[kk], ah[kk], acc);
            qa = cvt4(acc + bqv);
        }

        // ---- tile k: SWAPPED -> K[tok=c15][d=quad*4+r] ----
        {
            f32x4 acc = {0.f, 0.f, 0.f, 0.f};
            #pragma unroll
            for (int kk = 0; kk < 4; ++kk) acc = MFMA(Bk[kk], ah[kk], acc);
            ka = cvt4(acc + bkv);
        }

        // ---- tile v: normal -> V[tok=quad*4+r][d=c15]; v_blk in-register ----
        {
            f32x4 acc = {0.f, 0.f, 0.f, 0.f};
            #pragma unroll
            for (int kk = 0; kk < 4; ++kk) acc = MFMA(ah[kk], Bv[kk], acc);
            f32x4 b2 = {bq2, bq2, bq2, bq2};
            va = cvt4(acc + b2);
            float s = acc[0] + acc[1] + acc[2] + acc[3];
            s += __shfl_xor(s, 16);
            s += __shfl_xor(s, 32);
            vblk = s * 0.0625f + bq2;     // v_blk[d=c15] of head `wave`
        }

        // ---- tile gate (resident Bg): keep own column via shuffle ----
        {
            f32x4 acc = {0.f, 0.f, 0.f, 0.f};
            #pragma unroll
            for (int kk = 0; kk < 4; ++kk) acc = MFMA(ah[kk], Bg[kk], acc);
            const int src = (lane & 48) | wave;
            #pragma unroll
            for (int r = 0; r < 4; ++r) {
                float sg = sigmoid_fast(acc[r] + bgate);
                greg[r] = __shfl(sg, src);        // g[tok=quad*4+r][h=wave]
            }
        }
        __syncthreads();   // barrier B: ewS/logitS visible; xS reads done

        // stage NEXT block's x (overlaps attention; visibility via barrier C)
        if (more) {
            int row = tid >> 5, c4 = tid & 31;
            int off = row * 128 + (((c4 >> 1) ^ (row & 7)) << 3) + ((c4 & 1) << 2);
            f32x4 vv = {xv_n.x, xv_n.y, xv_n.z, xv_n.w};
            *(us4*)&xS[off] = cvt4u(vv);
        }

        // ---- attention (head h = wave), fully in-register ----
        {
            f32x4 sc = {0.f, 0.f, 0.f, 0.f};
            sc = MFMA16(ka, qa, sc);          // D[k=quad*4+r][q=c15]
            const f32x4 lg = *(const f32x4*)&logitS[c15 * 16 + quad * 4];
            const us4 ew4 = *(const us4*)&ewS[wave * 256 + c15 * 16 + quad * 4];
            // max-free softmax (|s| <~ 15, f32 exp safe; -inf -> 0)
            float e0 = __expf(__builtin_fmaf(sc[0], 0.25f, lg[0]));
            float e1 = __expf(__builtin_fmaf(sc[1], 0.25f, lg[1]));
            float e2 = __expf(__builtin_fmaf(sc[2], 0.25f, lg[2]));
            float e3 = __expf(__builtin_fmaf(sc[3], 0.25f, lg[3]));
            float sm = (e0 + e1) + (e2 + e3);
            sm += __shfl_xor(sm, 16);
            sm += __shfl_xor(sm, 32);
            const float inv = __builtin_amdgcn_rcpf(sm);
            f32x4 pv;
            pv[0] = __builtin_fmaf(e0, inv, bf2f(ew4[0]));
            pv[1] = __builtin_fmaf(e1, inv, bf2f(ew4[1]));
            pv[2] = __builtin_fmaf(e2, inv, bf2f(ew4[2]));
            pv[3] = __builtin_fmaf(e3, inv, bf2f(ew4[3]));
            bf16x4 pa = cvt4(pv);   // P fragment == scores D layout
            f32x4 xs = {0.f, 0.f, 0.f, 0.f};
            xs = MFMA16(pa, va, xs);          // D[q=quad*4+r][d=c15]
            f32x4 valv;
            #pragma unroll
            for (int r = 0; r < 4; ++r)
                valv[r] = xs[r] + greg[r] * vblk;
            us4 mm = cvt4u(valv);
            #pragma unroll
            for (int r = 0; r < 4; ++r) {
                const int tok = quad * 4 + r;
                mhiS[tok * 136 + wave * 16 + c15] = mm[r];
            }
        }
        __syncthreads();   // barrier C: x_mid + next-x staged visible

        // ---- output projection: SWAPPED (Wt as A, x_mid as B) -> f32x4 store ----
        {
            bf16x8 mh[4];
            #pragma unroll
            for (int kk = 0; kk < 4; ++kk)
                mh[kk] = *(const bf16x8*)&mhiS[c15 * 136 + kk * 32 + quad * 8];
            f32x4 acc = {0.f, 0.f, 0.f, 0.f};
            #pragma unroll
            for (int kk = 0; kk < 4; ++kk) acc = MFMA(Wt[kk], mh[kk], acc);
            // D[n=quad*4+r][tok=c15] -> out[tok][wave*16+quad*4+r] contiguous
            float* op = out + (size_t)bid * 2048;
            *(f32x4*)&op[c15 * 128 + wave * 16 + quad * 4] = acc + bpv4;
        }

        mvA = mvA_n; mvB = mvB_n;
        evA = evA_n; evB = evB_n;
    }
}

extern "C" void kernel_launch(void* const* d_in, const int* in_sizes, int n_in,
                              void* d_out, int out_size, void* d_ws, size_t ws_size,
                              hipStream_t stream) {
    const float* x     = (const float*)d_in[0];
    const int*   amask = (const int*)  d_in[1];
    const float* edge  = (const float*)d_in[2];
    const float* Wqkv  = (const float*)d_in[3];
    const float* bqkv  = (const float*)d_in[4];
    const float* Wproj = (const float*)d_in[5];
    const float* bproj = (const float*)d_in[6];
    const float* eg_w1 = (const float*)d_in[7];
    const float* eg_b1 = (const float*)d_in[8];
    const float* eg_w2 = (const float*)d_in[9];
    const float* eg_b2 = (const float*)d_in[10];
    const float* Wbr   = (const float*)d_in[11];
    const float* bbr   = (const float*)d_in[12];
    float* outp = (float*)d_out;

    hipLaunchKernelGGL(leaf_main, dim3(8192 / NITER), dim3(512), 0, stream,
                       x, amask, edge, Wqkv, bqkv, Wproj, bproj,
                       eg_w1, eg_b1, eg_w2, eg_b2, Wbr, bbr, outp);
}

// Round 25
// 78.458 us; speedup vs baseline: 1.0496x; 1.0496x over previous
//
#include <hip/hip_runtime.h>
#include <hip/hip_bf16.h>
#include <math.h>

// B=4, NB=2048 -> 8192 leaf blocks of L=16 tokens x C=128; H=8 heads x D=16.
// 512 threads (8 waves), NITER=16 blocks/WG (grid 512 = 2 WGs/CU), 2 barriers/iter.
// q/k via SWAPPED-operand MFMA (q/k/v/P in registers); Bq/Bk/Bv/Bg/Wt ALL
// register-resident; edge-gate MLP on matrix cores; ballot row-sum; max-free
// softmax; native packed f32->bf16 conversions; swapped proj -> f32x4 store.
// r25: pure revert to the measured optimum (r21/r22 structure, 78.8 us).
typedef __attribute__((ext_vector_type(8))) short bf16x8;
typedef __attribute__((ext_vector_type(4))) short bf16x4;
typedef __attribute__((ext_vector_type(4))) float f32x4;
typedef __attribute__((ext_vector_type(4))) unsigned short us4;
typedef __attribute__((ext_vector_type(4))) __bf16 bfv4;

#define NITER 16

static __device__ __forceinline__ unsigned short f2bf_rn(float f) {
    union { __hip_bfloat16 h; unsigned short u; } cv;
    cv.h = __float2bfloat16(f);
    return cv.u;
}
static __device__ __forceinline__ bf16x4 cvt4(f32x4 v) {
    union { bfv4 b; bf16x4 s; } u;
    u.b = __builtin_convertvector(v, bfv4);
    return u.s;
}
static __device__ __forceinline__ us4 cvt4u(f32x4 v) {
    union { bfv4 b; us4 s; } u;
    u.b = __builtin_convertvector(v, bfv4);
    return u.s;
}
static __device__ __forceinline__ float bf2f(unsigned short u) {
    union { unsigned int i; float f; } cv;
    cv.i = ((unsigned int)u) << 16;
    return cv.f;
}
static __device__ __forceinline__ f32x4 MFMA(bf16x8 a, bf16x8 b, f32x4 c) {
    return __builtin_amdgcn_mfma_f32_16x16x32_bf16(a, b, c, 0, 0, 0);
}
static __device__ __forceinline__ f32x4 MFMA16(bf16x4 a, bf16x4 b, f32x4 c) {
#if __has_builtin(__builtin_amdgcn_mfma_f32_16x16x16bf16_1k)
    return __builtin_amdgcn_mfma_f32_16x16x16bf16_1k(a, b, c, 0, 0, 0);
#elif __has_builtin(__builtin_amdgcn_mfma_f32_16x16x16_bf16)
    return __builtin_amdgcn_mfma_f32_16x16x16_bf16(a, b, c, 0, 0, 0);
#else
    f32x4 d;
    asm("v_mfma_f32_16x16x16_bf16 %0, %1, %2, %3"
        : "=v"(d) : "v"(a), "v"(b), "v"(c));
    return d;
#endif
}
static __device__ __forceinline__ float sigmoid_fast(float t) {
    return __builtin_amdgcn_rcpf(1.f + __expf(-t));
}

// ---- prep: Wbig = bf16([Wqkv(384); Wbr(8); zeros(8)]) [400][128]; Wp = bf16(Wproj)
__global__ __launch_bounds__(256) void prep_kernel(
    const float* __restrict__ Wqkv, const float* __restrict__ Wbr,
    const float* __restrict__ Wproj,
    unsigned short* __restrict__ Wbig, unsigned short* __restrict__ Wp)
{
    int i = blockIdx.x * 256 + threadIdx.x;
    if (i < 400 * 128) {
        int n = i >> 7, k = i & 127;
        float v = (n < 384) ? Wqkv[i] : (n < 392 ? Wbr[(n - 384) * 128 + k] : 0.f);
        Wbig[i] = f2bf_rn(v);
    } else {
        int j = i - 400 * 128;
        if (j < 128 * 128) Wp[j] = f2bf_rn(Wproj[j]);
    }
}

__global__ __launch_bounds__(512) void leaf_main(
    const float* __restrict__ x, const int* __restrict__ mask,
    const float* __restrict__ edge,
    const unsigned short* __restrict__ Wbig, const unsigned short* __restrict__ Wp,
    const float* __restrict__ bqkv, const float* __restrict__ bproj,
    const float* __restrict__ eg_w1, const float* __restrict__ eg_b1,
    const float* __restrict__ eg_w2, const float* __restrict__ eg_b2,
    const float* __restrict__ bbr, float* __restrict__ out)
{
    __shared__ unsigned short xS[16 * 128];      // x stage (bf16, swizzled)
    __shared__ unsigned short mhiS[16 * 136];    // x_mid rounded bf16
    __shared__ unsigned short ewS[8 * 256];      // [h][q*16+k]
    __shared__ float logitS[256];                // [q*16+k]
    // total ~14.3 KB

    const int tid  = threadIdx.x;
    const int lane = tid & 63;
    const int wave = tid >> 6;
    const int c15  = lane & 15;
    const int quad = lane >> 4;
    const int bid0 = blockIdx.x * NITER;
    const int t0 = wave * 2, t1 = wave * 2 + 1;   // this wave's q-row tiles

    // iteration-invariant scalars (q/k biases are per-d = quad*4+r based)
    const f32x4 bqv = *(const f32x4*)&bqkv[wave * 16 + quad * 4];
    const f32x4 bkv = *(const f32x4*)&bqkv[128 + wave * 16 + quad * 4];
    const float bq2 = bqkv[256 + wave * 16 + c15];
    const float bgate = bbr[c15 & 7];
    const f32x4 bpv4 = *(const f32x4*)&bproj[wave * 16 + quad * 4];

    // ---- resident MLP fragments (uniform) ----
    bf16x4 W1a = {0, 0, 0, 0};    // A[row=j=c15][k=quad*4+r] (k<4 valid)
    if (quad == 0) {
        const f32x4 w1 = *(const f32x4*)&eg_w1[c15 * 4];
        W1a = cvt4(w1);
    }
    bf16x4 W2a = {0, 0, 0, 0};    // A[row=h=c15][k=j=quad*4+r] (h<8 valid)
    if (c15 < 8) {
        const f32x4 w2 = *(const f32x4*)&eg_w2[c15 * 16 + quad * 4];
        W2a = cvt4(w2);
    }
    const f32x4 b1v = *(const f32x4*)&eg_b1[quad * 4];
    f32x4 b2v = {0.f, 0.f, 0.f, 0.f};
    if (quad < 2) b2v = *(const f32x4*)&eg_b2[quad * 4];

    // ---- REGISTER-RESIDENT weight tiles (once per WG; natural allocation) ----
    const unsigned short* wbase = Wbig + c15 * 128 + quad * 8;
    bf16x8 Bq[4], Bk[4], Bv[4], Bg[4], Wt[4];
    {
        const unsigned short* wq = wbase + (wave * 16) * 128;
        const unsigned short* wk = wbase + ((8 + wave) * 16) * 128;
        const unsigned short* wv = wbase + ((16 + wave) * 16) * 128;
        const unsigned short* wgp = wbase + 384 * 128;
        const unsigned short* wp = Wp + (wave * 16 + c15) * 128 + quad * 8;
        #pragma unroll
        for (int kk = 0; kk < 4; ++kk) {
            Bq[kk] = *(const bf16x8*)(wq + kk * 32);
            Bk[kk] = *(const bf16x8*)(wk + kk * 32);
            Bv[kk] = *(const bf16x8*)(wv + kk * 32);
            Bg[kk] = *(const bf16x8*)(wgp + kk * 32);
            Wt[kk] = *(const bf16x8*)(wp + kk * 32);
        }
    }

    // prologue: block 0 inputs (mask/edge on quad-0 lanes only)
    int mvA = 0, mvB = 0;
    float4 evA = make_float4(0.f, 0.f, 0.f, 0.f);
    float4 evB = make_float4(0.f, 0.f, 0.f, 0.f);
    if (quad == 0) {
        const size_t base = (size_t)bid0 * 256;
        mvA = mask[base + t0 * 16 + c15];
        mvB = mask[base + t1 * 16 + c15];
        evA = *(const float4*)&edge[(base + t0 * 16 + c15) * 4];
        evB = *(const float4*)&edge[(base + t1 * 16 + c15) * 4];
    }
    float4 xv = ((const float4*)(x + (size_t)bid0 * 2048))[tid];
    {
        int row = tid >> 5, c4 = tid & 31;
        int off = row * 128 + (((c4 >> 1) ^ (row & 7)) << 3) + ((c4 & 1) << 2);
        f32x4 vv = {xv.x, xv.y, xv.z, xv.w};
        *(us4*)&xS[off] = cvt4u(vv);
    }
    __syncthreads();   // prologue barrier: x0 staged

    #pragma unroll 1
    for (int it = 0; it < NITER; ++it) {
        const int bid = bid0 + it;
        const bool more = (it + 1 < NITER);

        // next-block loads (retire under this iteration's compute)
        float4 xv_n = make_float4(0.f, 0.f, 0.f, 0.f);
        int mvA_n = 0, mvB_n = 0;
        float4 evA_n = make_float4(0.f, 0.f, 0.f, 0.f);
        float4 evB_n = make_float4(0.f, 0.f, 0.f, 0.f);
        if (more) {
            xv_n = ((const float4*)(x + (size_t)(bid + 1) * 2048))[tid];
            if (quad == 0) {
                const size_t base = (size_t)(bid + 1) * 256;
                mvA_n = mask[base + t0 * 16 + c15];
                mvB_n = mask[base + t1 * 16 + c15];
                evA_n = *(const float4*)&edge[(base + t0 * 16 + c15) * 4];
                evB_n = *(const float4*)&edge[(base + t1 * 16 + c15) * 4];
            }
        }

        // ---- edge-gate MLP on matrix cores: two q-row tiles per wave ----
        #pragma unroll
        for (int tt = 0; tt < 2; ++tt) {
            const int t = tt ? t1 : t0;
            const int mvt = tt ? mvB : mvA;
            const float4 evt = tt ? evB : evA;
            // layer-1 B fragment: B[k=quad*4+r][col=pair_in_row=c15]
            bf16x4 bpB = {0, 0, 0, 0};
            float bp3 = 0.f;
            if (quad == 0) {
                const bool diag = (c15 == t);
                bp3 = diag ? 1.f : evt.w;
                f32x4 bpf = {diag ? 0.f : evt.x, diag ? 0.f : evt.y,
                             diag ? 0.f : evt.z, bp3};
                bpB = cvt4(bpf);
            }
            // mask row (tile == q-row): one ballot, uniform result
            const unsigned long long bl = __ballot(quad == 0 && mvt != 0);
            const unsigned m16 = (unsigned)(bl & 0xFFFFull);
            const bool meff = ((m16 >> c15) & 1u) || (m16 == 0u && c15 == t);
            if (quad == 0)
                logitS[t * 16 + c15] = meff ? bp3 : -INFINITY;
            // hT[j=quad*4+r][pair=c15] = W1 @ bpT  (+b1, gelu)
            f32x4 h1 = {0.f, 0.f, 0.f, 0.f};
            h1 = MFMA16(W1a, bpB, h1);
            f32x4 gv;
            #pragma unroll
            for (int r = 0; r < 4; ++r) {
                float z = h1[r] + b1v[r];
                float u = z * z;
                float w = __builtin_fmaf(-0.0664904f, u, 0.3989423f);
                gv[r] = z * __builtin_fmaf(z, w, 0.5f);
            }
            bf16x4 hB = cvt4(gv);
            // ewT[h=quad*4+r][pair=c15] = W2 @ hT (+b2)
            f32x4 e2 = {0.f, 0.f, 0.f, 0.f};
            e2 = MFMA16(W2a, hB, e2);
            if (quad < 2) {
                #pragma unroll
                for (int r = 0; r < 4; ++r) {
                    float ewv = e2[r] + b2v[r];
                    ewS[(quad * 4 + r) * 256 + t * 16 + c15] =
                        meff ? (unsigned short)(__float_as_uint(ewv) >> 16)
                             : (unsigned short)0;
                }
            }
        }

        // ---- x fragments from xS (serve as A or B operand) ----
        bf16x8 ah[4];
        #pragma unroll
        for (int kk = 0; kk < 4; ++kk) {
            int off = c15 * 128 + (((kk * 4 + quad) ^ (c15 & 7)) << 3);
            ah[kk] = *(const bf16x8*)&xS[off];
        }

        bf16x4 qa, ka, va;
        float vblk;
        float greg[4];

        // ---- tile q: SWAPPED (W as A, x as B) -> Q[tok=c15][d=quad*4+r] ----
        {
            f32x4 acc = {0.f, 0.f, 0.f, 0.f};
            #pragma unroll
            for (int kk = 0; kk < 4; ++kk) acc = MFMA(Bq[kk], ah[kk], acc);
            qa = cvt4(acc + bqv);
        }

        // ---- tile k: SWAPPED -> K[tok=c15][d=quad*4+r] ----
        {
            f32x4 acc = {0.f, 0.f, 0.f, 0.f};
            #pragma unroll
            for (int kk = 0; kk < 4; ++kk) acc = MFMA(Bk[kk], ah[kk], acc);
            ka = cvt4(acc + bkv);
        }

        // ---- tile v: normal -> V[tok=quad*4+r][d=c15]; v_blk in-register ----
        {
            f32x4 acc = {0.f, 0.f, 0.f, 0.f};
            #pragma unroll
            for (int kk = 0; kk < 4; ++kk) acc = MFMA(ah[kk], Bv[kk], acc);
            f32x4 b2 = {bq2, bq2, bq2, bq2};
            va = cvt4(acc + b2);
            float s = acc[0] + acc[1] + acc[2] + acc[3];
            s += __shfl_xor(s, 16);
            s += __shfl_xor(s, 32);
            vblk = s * 0.0625f + bq2;     // v_blk[d=c15] of head `wave`
        }

        // ---- tile gate (resident Bg): keep own column via shuffle ----
        {
            f32x4 acc = {0.f, 0.f, 0.f, 0.f};
            #pragma unroll
            for (int kk = 0; kk < 4; ++kk) acc = MFMA(ah[kk], Bg[kk], acc);
            const int src = (lane & 48) | wave;
            #pragma unroll
            for (int r = 0; r < 4; ++r) {
                float sg = sigmoid_fast(acc[r] + bgate);
                greg[r] = __shfl(sg, src);        // g[tok=quad*4+r][h=wave]
            }
        }
        __syncthreads();   // barrier B: ewS/logitS visible; xS reads done

        // stage NEXT block's x (overlaps attention; visibility via barrier C)
        if (more) {
            int row = tid >> 5, c4 = tid & 31;
            int off = row * 128 + (((c4 >> 1) ^ (row & 7)) << 3) + ((c4 & 1) << 2);
            f32x4 vv = {xv_n.x, xv_n.y, xv_n.z, xv_n.w};
            *(us4*)&xS[off] = cvt4u(vv);
        }

        // ---- attention (head h = wave), fully in-register ----
        {
            f32x4 sc = {0.f, 0.f, 0.f, 0.f};
            sc = MFMA16(ka, qa, sc);          // D[k=quad*4+r][q=c15]
            const f32x4 lg = *(const f32x4*)&logitS[c15 * 16 + quad * 4];
            const us4 ew4 = *(const us4*)&ewS[wave * 256 + c15 * 16 + quad * 4];
            // max-free softmax (|s| <~ 15, f32 exp safe; -inf -> 0)
            float e0 = __expf(__builtin_fmaf(sc[0], 0.25f, lg[0]));
            float e1 = __expf(__builtin_fmaf(sc[1], 0.25f, lg[1]));
            float e2 = __expf(__builtin_fmaf(sc[2], 0.25f, lg[2]));
            float e3 = __expf(__builtin_fmaf(sc[3], 0.25f, lg[3]));
            float sm = (e0 + e1) + (e2 + e3);
            sm += __shfl_xor(sm, 16);
            sm += __shfl_xor(sm, 32);
            const float inv = __builtin_amdgcn_rcpf(sm);
            f32x4 pv;
            pv[0] = __builtin_fmaf(e0, inv, bf2f(ew4[0]));
            pv[1] = __builtin_fmaf(e1, inv, bf2f(ew4[1]));
            pv[2] = __builtin_fmaf(e2, inv, bf2f(ew4[2]));
            pv[3] = __builtin_fmaf(e3, inv, bf2f(ew4[3]));
            bf16x4 pa = cvt4(pv);   // P fragment == scores D layout
            f32x4 xs = {0.f, 0.f, 0.f, 0.f};
            xs = MFMA16(pa, va, xs);          // D[q=quad*4+r][d=c15]
            f32x4 valv;
            #pragma unroll
            for (int r = 0; r < 4; ++r)
                valv[r] = xs[r] + greg[r] * vblk;
            us4 mm = cvt4u(valv);
            #pragma unroll
            for (int r = 0; r < 4; ++r) {
                const int tok = quad * 4 + r;
                mhiS[tok * 136 + wave * 16 + c15] = mm[r];
            }
        }
        __syncthreads();   // barrier C: x_mid + next-x staged visible

        // ---- output projection: SWAPPED (Wt as A, x_mid as B) -> f32x4 store ----
        {
            bf16x8 mh[4];
            #pragma unroll
            for (int kk = 0; kk < 4; ++kk)
                mh[kk] = *(const bf16x8*)&mhiS[c15 * 136 + kk * 32 + quad * 8];
            f32x4 acc = {0.f, 0.f, 0.f, 0.f};
            #pragma unroll
            for (int kk = 0; kk < 4; ++kk) acc = MFMA(Wt[kk], mh[kk], acc);
            // D[n=quad*4+r][tok=c15] -> out[tok][wave*16+quad*4+r] contiguous
            float* op = out + (size_t)bid * 2048;
            *(f32x4*)&op[c15 * 128 + wave * 16 + quad * 4] = acc + bpv4;
        }

        mvA = mvA_n; mvB = mvB_n;
        evA = evA_n; evB = evB_n;
    }
}

extern "C" void kernel_launch(void* const* d_in, const int* in_sizes, int n_in,
                              void* d_out, int out_size, void* d_ws, size_t ws_size,
                              hipStream_t stream) {
    const float* x     = (const float*)d_in[0];
    const int*   amask = (const int*)  d_in[1];
    const float* edge  = (const float*)d_in[2];
    const float* Wqkv  = (const float*)d_in[3];
    const float* bqkv  = (const float*)d_in[4];
    const float* Wproj = (const float*)d_in[5];
    const float* bproj = (const float*)d_in[6];
    const float* eg_w1 = (const float*)d_in[7];
    const float* eg_b1 = (const float*)d_in[8];
    const float* eg_w2 = (const float*)d_in[9];
    const float* eg_b2 = (const float*)d_in[10];
    const float* Wbr   = (const float*)d_in[11];
    const float* bbr   = (const float*)d_in[12];
    float* outp = (float*)d_out;

    unsigned short* Wbig = (unsigned short*)d_ws;                      // 400*128 bf16
    unsigned short* Wp   = (unsigned short*)((char*)d_ws + 400 * 128 * 2);

    hipLaunchKernelGGL(prep_kernel, dim3(264), dim3(256), 0, stream,
                       Wqkv, Wbr, Wproj, Wbig, Wp);
    hipLaunchKernelGGL(leaf_main, dim3(8192 / NITER), dim3(512), 0, stream,
                       x, amask, edge, Wbig, Wp, bqkv, bproj,
                       eg_w1, eg_b1, eg_w2, eg_b2, bbr, outp);
}